// Round 7
// baseline (10.454 us; speedup 1.0000x reference)
//
#include <hip/hip_runtime.h>

#define NF 8
#define DEG 4
#define NTERMS 495

// ---------------------------------------------------------------------------
// Compile-time combinatorics: sub-polynomial over vars x_F..x_{NF-1} with
// total degree <= REM has subcnt(F,REM) = C(NF-F+REM, REM) coefficients
// (lexicographic order, e0 slowest..e7 fastest, matching the reference
// meshgrid enumeration -- verified by the passing R2/R4/R5/R6 kernels).
// ---------------------------------------------------------------------------
constexpr long long nCkll(int n, int k) {
    long long r = 1;
    for (int i = 1; i <= k; ++i) r = r * (n - k + i) / i;
    return r;
}
constexpr int subcnt(int F, int REM) { return (int)nCkll(NF - F + REM, REM); }

constexpr int csum(int F, int REM, int E) {
    int s = 0;
    for (int j = 0; j < E; ++j) s += subcnt(F + 1, REM - j);
    return s;
}

// facs[t] = 1/k! with k = total degree of term t -- COMPILE-TIME known.
// Match numpy: (1.0 / factorial) computed in f64, rounded to f32.
constexpr float facval(int k) {
    return (k <= 1) ? 1.0f
         : (k == 2) ? 0.5f
         : (k == 3) ? (float)(1.0 / 6.0)
         :            (float)(1.0 / 24.0);
}

// ---------------------------------------------------------------------------
// Full multivariate Horner (494 FMAs, each coefficient touched exactly once,
// term indices consumed in exact DESCENDING order T0 = 494..0).
// Coefficients are read DIRECTLY from global coefs via wave-uniform loads at
// compile-time offsets (float4 quads, first touch at lane .w since order is
// descending; 3-element tail 492..494 as scalars). Uniform + invariant +
// constexpr offset -> scalar s_load_dwordx4 candidates (scalar pipe, no LDS,
// no barrier, no fill phase). The 1/k! factor is folded as a compile-time
// constant multiply at the leaf (skipped for k<2).
// ---------------------------------------------------------------------------
template<int F, int REM, int T0> struct HNode;
template<int F, int REM, int E, int T0> struct HChain;

template<int F, int REM, int T0>
struct HNode {
    static __device__ __forceinline__ float eval(const float* xs,
                                                 const float* __restrict__ cf,
                                                 float4& wq) {
        float acc = HNode<F + 1, 0, T0 + csum(F, REM, REM)>::eval(xs, cf, wq);
        if constexpr (REM > 0)
            acc = HChain<F, REM, REM - 1, T0>::step(acc, xs, cf, wq);
        return acc;
    }
};

// leaf: coefficient at compile-time term index T0; term degree k = DEG - REM
template<int REM, int T0>
struct HNode<NF, REM, T0> {
    static __device__ __forceinline__ float eval(const float*,
                                                 const float* __restrict__ cf,
                                                 float4& wq) {
        constexpr int K = DEG - REM;
        float w;
        if constexpr (T0 >= (NTERMS & ~3)) {
            w = cf[T0];                       // tail 492..494, scalar uniform load
        } else {
            if constexpr ((T0 & 3) == 3)
                wq = ((const float4*)cf)[T0 >> 2];   // first touch (descending)
            constexpr int c = T0 & 3;
            w = (c == 0) ? wq.x : (c == 1) ? wq.y : (c == 2) ? wq.z : wq.w;
        }
        if constexpr (K >= 2) w *= facval(K);
        return w;
    }
};

template<int F, int REM, int E, int T0>
struct HChain {
    static __device__ __forceinline__ float step(float acc, const float* xs,
                                                 const float* __restrict__ cf,
                                                 float4& wq) {
        float c = HNode<F + 1, REM - E, T0 + csum(F, REM, E)>::eval(xs, cf, wq);
        acc = fmaf(acc, xs[F], c);
        if constexpr (E > 0)
            return HChain<F, REM, E - 1, T0>::step(acc, xs, cf, wq);
        else
            return acc;
    }
};

__global__ __launch_bounds__(256, 1)
void maclaurin_fused(const float* __restrict__ x,
                     const float* __restrict__ coefs,
                     float* __restrict__ out, int n) {
    const int b = blockIdx.x * blockDim.x + threadIdx.x;

    float xs[NF];
    if (b < n) {
        const float4* xp = (const float4*)(x + (size_t)b * NF);
        float4 v0 = xp[0];
        float4 v1 = xp[1];
        xs[0] = v0.x; xs[1] = v0.y; xs[2] = v0.z; xs[3] = v0.w;
        xs[4] = v1.x; xs[5] = v1.y; xs[6] = v1.z; xs[7] = v1.w;
    } else {
        #pragma unroll
        for (int f = 0; f < NF; ++f) xs[f] = 0.0f;
    }

    float4 wq;
    float r = HNode<0, DEG, 0>::eval(xs, coefs, wq);

    if (b < n) out[b] = r;
}

// ---------------------------------------------------------------------------
// launch
// ---------------------------------------------------------------------------
extern "C" void kernel_launch(void* const* d_in, const int* in_sizes, int n_in,
                              void* d_out, int out_size, void* d_ws, size_t ws_size,
                              hipStream_t stream) {
    // inputs (setup_inputs order): x [B,8] f32, terms [495,8] f32,
    //                              coefs [1,495] f32, facs [495] f32
    // terms and facs are compile-time constants of the problem (terms is the
    // meshgrid enumeration; facs = 1/k! by total degree) -- folded into the
    // kernel; only x and coefs are read at runtime.
    const float* x     = (const float*)d_in[0];
    const float* coefs = (const float*)d_in[2];
    float* out = (float*)d_out;

    int n = in_sizes[0] / NF;    // 65536

    maclaurin_fused<<<(n + 255) / 256, 256, 0, stream>>>(x, coefs, out, n);
}

// Round 8
// 9.521 us; speedup vs baseline: 1.0980x; 1.0980x over previous
//
#include <hip/hip_runtime.h>

#define NF 8
#define DEG 4
#define NTERMS 495

// Constant-address-space pointer: loads at wave-uniform constexpr offsets
// select s_load_dwordxN (scalar cache -> SGPRs), not per-lane VMEM.
typedef __attribute__((address_space(4))) const float cfloat;

// ---------------------------------------------------------------------------
// Compile-time combinatorics: sub-polynomial over vars x_F..x_{NF-1} with
// total degree <= REM has subcnt(F,REM) = C(NF-F+REM, REM) coefficients
// (lexicographic order, e0 slowest..e7 fastest, matching the reference
// meshgrid enumeration -- verified by the passing R2/R4/R5/R6/R7 kernels).
// ---------------------------------------------------------------------------
constexpr long long nCkll(int n, int k) {
    long long r = 1;
    for (int i = 1; i <= k; ++i) r = r * (n - k + i) / i;
    return r;
}
constexpr int subcnt(int F, int REM) { return (int)nCkll(NF - F + REM, REM); }

constexpr int csum(int F, int REM, int E) {
    int s = 0;
    for (int j = 0; j < E; ++j) s += subcnt(F + 1, REM - j);
    return s;
}

// ---------------------------------------------------------------------------
// TELESCOPED-FACTORIAL multivariate Horner.
// Chain at node (F,REM) has prefix degree p = DEG-REM (degree already
// committed by ancestors). The step that multiplies past child E uses
// x_F/(p+E+1). A leaf of total degree k passes divisors that telescope to
// exactly 1/k!  =>  facs is folded away entirely; coefficients are consumed
// RAW, each exactly once: 494 FMAs total. Scaled variants x_f/{1,2,3,4} are
// precomputed once (24 muls). All indices constant-fold (rule #20 safe).
// Term indices consumed in descending order T0 = 494..0; adjacent constexpr
// offsets let the compiler merge the AS4 loads into s_load_dwordx8/x16.
// ---------------------------------------------------------------------------
template<int F, int REM, int T0> struct HNode;
template<int F, int REM, int E, int T0> struct HChain;

template<int F, int REM, int T0>
struct HNode {
    static __device__ __forceinline__ float eval(const float (&xsc)[NF][DEG],
                                                 cfloat* cw) {
        float acc = HNode<F + 1, 0, T0 + csum(F, REM, REM)>::eval(xsc, cw);
        if constexpr (REM > 0)
            acc = HChain<F, REM, REM - 1, T0>::step(acc, xsc, cw);
        return acc;
    }
};

// leaf: raw coefficient at compile-time term index T0 (uniform s_load)
template<int REM, int T0>
struct HNode<NF, REM, T0> {
    static __device__ __forceinline__ float eval(const float (&)[NF][DEG],
                                                 cfloat* cw) {
        return cw[T0];
    }
};

template<int F, int REM, int E, int T0>
struct HChain {
    static __device__ __forceinline__ float step(float acc,
                                                 const float (&xsc)[NF][DEG],
                                                 cfloat* cw) {
        float c = HNode<F + 1, REM - E, T0 + csum(F, REM, E)>::eval(xsc, cw);
        constexpr int P = DEG - REM;            // prefix degree of this node
        acc = fmaf(acc, xsc[F][P + E], c);      // multiplier x_F/(P+E+1)
        if constexpr (E > 0)
            return HChain<F, REM, E - 1, T0>::step(acc, xsc, cw);
        else
            return acc;
    }
};

__global__ __launch_bounds__(256, 1)
void maclaurin_fused(const float* __restrict__ x,
                     const float* __restrict__ coefs,
                     float* __restrict__ out, int n) {
    const int b = blockIdx.x * blockDim.x + threadIdx.x;

    float xs[NF];
    if (b < n) {
        const float4* xp = (const float4*)(x + (size_t)b * NF);
        float4 v0 = xp[0];
        float4 v1 = xp[1];
        xs[0] = v0.x; xs[1] = v0.y; xs[2] = v0.z; xs[3] = v0.w;
        xs[4] = v1.x; xs[5] = v1.y; xs[6] = v1.z; xs[7] = v1.w;
    } else {
        #pragma unroll
        for (int f = 0; f < NF; ++f) xs[f] = 0.0f;
    }

    // scaled variants x_f / m, m = 1..DEG (indices constexpr -> registers)
    float xsc[NF][DEG];
    #pragma unroll
    for (int f = 0; f < NF; ++f) {
        xsc[f][0] = xs[f];
        xsc[f][1] = xs[f] * 0.5f;
        xsc[f][2] = xs[f] * (1.0f / 3.0f);
        xsc[f][3] = xs[f] * 0.25f;
    }

    cfloat* cw = (cfloat*)(unsigned long long)(const void*)coefs;

    float r = HNode<0, DEG, 0>::eval(xsc, cw);

    if (b < n) out[b] = r;
}

// ---------------------------------------------------------------------------
// launch
// ---------------------------------------------------------------------------
extern "C" void kernel_launch(void* const* d_in, const int* in_sizes, int n_in,
                              void* d_out, int out_size, void* d_ws, size_t ws_size,
                              hipStream_t stream) {
    // inputs (setup_inputs order): x [B,8] f32, terms [495,8] f32,
    //                              coefs [1,495] f32, facs [495] f32
    // terms is the compile-time meshgrid enumeration; facs = 1/k! is folded
    // into the telescoped Horner multipliers. Only x and coefs are read.
    const float* x     = (const float*)d_in[0];
    const float* coefs = (const float*)d_in[2];
    float* out = (float*)d_out;

    int n = in_sizes[0] / NF;    // 65536

    maclaurin_fused<<<(n + 255) / 256, 256, 0, stream>>>(x, coefs, out, n);
}